// Round 6
// baseline (226.311 us; speedup 1.0000x reference)
//
#include <hip/hip_runtime.h>
#include <math.h>

#define N_NODES 8192
#define D_FEAT  512
#define H_HEADS 8
#define DKH     64
#define DEG     16
#define E_EDGES (N_NODES * DEG)
#define FEAT_W  576      // 544 used (8*(64+4)) + 32 pad for K%64==0
#define FEAT_USED 544
#define OUT_W   512
#define QKV_W   1664     // 512 q | 512 k | 512 v | 24 qv | 104 pad  (13*128)

typedef unsigned short u16;
typedef __attribute__((ext_vector_type(8))) short short8;   // 8 bf16 for MFMA
typedef __attribute__((ext_vector_type(8))) unsigned short us8;
typedef __attribute__((ext_vector_type(4))) float f32x4;

// ---- bf16 helpers (RNE) ----------------------------------------------------
__device__ __forceinline__ u16 f2bf(float f) {
    union { float f; unsigned u; } c; c.f = f;
    unsigned u = c.u;
    unsigned r = u + 0x7FFFu + ((u >> 16) & 1u);
    return (u16)(r >> 16);
}
__device__ __forceinline__ float bf2f(u16 h) {
    union { unsigned u; float f; } c; c.u = ((unsigned)h) << 16;
    return c.f;
}

// ---- async global->LDS 16B (HW: lds dest = wave-uniform base + lane*16) ----
__device__ __forceinline__ void async16(const void* g, void* l) {
    __builtin_amdgcn_global_load_lds(
        (const __attribute__((address_space(1))) void*)g,
        (__attribute__((address_space(3))) void*)l, 16, 0, 0);
}

// ---------------------------------------------------------------------------
// bf16 MFMA GEMM, BK=64: C[M,N] = A[M,K]*B[N,K]^T (+bias). Optional split-B
// second pass (B = Bh + Bl). M%128==0, N%128==0, K%64==0.
// 256 threads = 4 waves; 128x128 tile.
// LDS tiles are [128][64] u16 with the 16B-chunk index XOR-swizzled by
// (row&7) to kill the 128B-stride bank conflicts on ds_read_b128. Because
// global_load_lds writes base+lane*16, the swizzle is applied to the
// *global source address* (permuting which chunk each lane fetches).
// ---------------------------------------------------------------------------
template<bool HAS_BL, bool BF16_OUT>
__global__ __launch_bounds__(256) void gemm_mfma(
    const u16* __restrict__ Ah,
    const u16* __restrict__ Bh, const u16* __restrict__ Bl,
    const float* __restrict__ bias, void* __restrict__ Cout,
    int M, int N, int K)
{
    constexpr int NMAT = HAS_BL ? 3 : 2;
    __shared__ u16 smem[128 * 64 * NMAT];
    u16* sAh = smem;
    u16* sBh = smem + 128 * 64;
    u16* sBl = smem + 128 * 64 * 2;   // used only if HAS_BL

    const int tid  = threadIdx.x;
    const int bm   = blockIdx.y * 128;
    const int bn   = blockIdx.x * 128;
    const int wave = tid >> 6;
    const int lane = tid & 63;
    const int wr   = (wave >> 1) * 64;
    const int wc   = (wave & 1) * 64;
    const int lrow = lane & 15;
    const int quad = lane >> 4;

    f32x4 acc[4][4];
    #pragma unroll
    for (int i = 0; i < 4; ++i)
        #pragma unroll
        for (int j = 0; j < 4; ++j) {
            f32x4 z = {0.f, 0.f, 0.f, 0.f};
            acc[i][j] = z;
        }

    for (int k0 = 0; k0 < K; k0 += 64) {
        // Stage 128x64 u16 per matrix = 1024 16B chunks; 4 per thread each.
        #pragma unroll
        for (int i = 0; i < 4; ++i) {
            const int lin = i * 256 + tid;            // LDS chunk slot 0..1023
            const int row = lin >> 3;                 // 0..127
            const int cs  = lin & 7;                  // swizzled chunk in row
            const int cu  = cs ^ (row & 7);           // unswizzled k-chunk
            const int seg = cu << 3;                  // k element offset
            const int loff = lin << 3;                // == lane-linear 16B
            const size_t ga = (size_t)(bm + row) * K + k0 + seg;
            const size_t gb = (size_t)(bn + row) * K + k0 + seg;
            async16(Ah + ga, sAh + loff);
            async16(Bh + gb, sBh + loff);
            if (HAS_BL) async16(Bl + gb, sBl + loff);
        }
        __syncthreads();

        #pragma unroll
        for (int ko = 0; ko < 64; ko += 32) {
            const int cbase = ko >> 3;                // 0 or 4
            short8 a_h[4], b_h[4], b_l[4];
            #pragma unroll
            for (int t = 0; t < 4; ++t) {
                const int ra = wr + t * 16 + lrow;
                const int rb = wc + t * 16 + lrow;
                const int ca = ((cbase + quad) ^ (ra & 7)) << 3;
                const int cb = ((cbase + quad) ^ (rb & 7)) << 3;
                a_h[t] = *(const short8*)&sAh[ra * 64 + ca];
                b_h[t] = *(const short8*)&sBh[rb * 64 + cb];
                if (HAS_BL) b_l[t] = *(const short8*)&sBl[rb * 64 + cb];
            }
            #pragma unroll
            for (int mt = 0; mt < 4; ++mt)
                #pragma unroll
                for (int nt = 0; nt < 4; ++nt) {
                    acc[mt][nt] = __builtin_amdgcn_mfma_f32_16x16x32_bf16(
                        a_h[mt], b_h[nt], acc[mt][nt], 0, 0, 0);
                    if (HAS_BL)
                        acc[mt][nt] = __builtin_amdgcn_mfma_f32_16x16x32_bf16(
                            a_h[mt], b_l[nt], acc[mt][nt], 0, 0, 0);
                }
        }
        __syncthreads();
    }

    // C/D layout: col = lane&15, row = quad*4 + r
    #pragma unroll
    for (int nt = 0; nt < 4; ++nt) {
        const int col = bn + wc + nt * 16 + lrow;
        const float bb = bias ? bias[col] : 0.f;
        #pragma unroll
        for (int mt = 0; mt < 4; ++mt) {
            #pragma unroll
            for (int r = 0; r < 4; ++r) {
                const int row = bm + wr + mt * 16 + quad * 4 + r;
                const float v = acc[mt][nt][r] + bb;
                if (BF16_OUT)
                    ((u16*)Cout)[(size_t)row * N + col] = f2bf(v);
                else
                    ((float*)Cout)[(size_t)row * N + col] = v;
            }
        }
    }
}

// ---------------------------------------------------------------------------
// Fused prep: block-range partition over three jobs.
//  blocks [0, 4096)      : x fp32 -> bf16                 (1048576 ushort4)
//  blocks [4096, 4928)   : build fused B [1664,512]       (212992 ushort4)
//  blocks [4928, 5216)   : Wout -> (hi,lo) [512,576] pad0 (73728 ushort4)
// ---------------------------------------------------------------------------
__global__ __launch_bounds__(256) void prep_kernel(
    const float* __restrict__ x,
    const float* __restrict__ Wq, const float* __restrict__ Wk,
    const float* __restrict__ Wv, const float* __restrict__ Wqv,
    const float* __restrict__ Wout,
    u16* __restrict__ xh, u16* __restrict__ B,
    u16* __restrict__ Woth, u16* __restrict__ Wotl)
{
    const int b = blockIdx.x;
    const int tid = threadIdx.x;
    if (b < 4096) {
        const int i = b * 256 + tid;                 // < 1048576
        const float4 v = ((const float4*)x)[i];
        ushort4 h;
        h.x = f2bf(v.x); h.y = f2bf(v.y); h.z = f2bf(v.z); h.w = f2bf(v.w);
        ((ushort4*)xh)[i] = h;
    } else if (b < 4928) {
        const int idx = (b - 4096) * 256 + tid;      // < 212992
        const int row = idx >> 7;
        const int c4  = idx & 127;
        float4 v = make_float4(0.f, 0.f, 0.f, 0.f);
        float scale = 1.f;
        if (row < 512) {
            v = *(const float4*)(Wq + (size_t)row * 512 + c4 * 4);
            scale = 0.125f;                          // 1/sqrt(64) folded into Wq
        } else if (row < 1024) {
            v = *(const float4*)(Wk + (size_t)(row - 512) * 512 + c4 * 4);
        } else if (row < 1536) {
            v = *(const float4*)(Wv + (size_t)(row - 1024) * 512 + c4 * 4);
        } else if (row < 1560) {
            v = *(const float4*)(Wqv + (size_t)(row - 1536) * 512 + c4 * 4);
        }
        ushort4 h;
        h.x = f2bf(v.x * scale); h.y = f2bf(v.y * scale);
        h.z = f2bf(v.z * scale); h.w = f2bf(v.w * scale);
        ((ushort4*)B)[idx] = h;
    } else {
        const int i = (b - 4928) * 256 + tid;        // < 73728 = 512*576/4
        if (i >= OUT_W * FEAT_W / 4) return;
        const int row = i / (FEAT_W / 4);            // /144
        const int c4  = i % (FEAT_W / 4);
        float4 v = make_float4(0.f, 0.f, 0.f, 0.f);
        if (c4 < FEAT_USED / 4)                      // pad cols 544..575 = 0
            v = *(const float4*)(Wout + (size_t)row * FEAT_USED + c4 * 4);
        ushort4 h, l;
        h.x = f2bf(v.x); l.x = f2bf(v.x - bf2f(h.x));
        h.y = f2bf(v.y); l.y = f2bf(v.y - bf2f(h.y));
        h.z = f2bf(v.z); l.z = f2bf(v.z - bf2f(h.z));
        h.w = f2bf(v.w); l.w = f2bf(v.w - bf2f(h.w));
        ((ushort4*)Woth)[i] = h;
        ((ushort4*)Wotl)[i] = l;
    }
}

// ---------------------------------------------------------------------------
// Edge stage: TWO NODES PER WAVE, two-pass re-gather (no LDS).
// lane = h*8+sub owns dims [lane*8, lane*8+8) of the 512-dim row.
// Metadata: lane group g=lane>>4; g&1 selects node; j16=lane&15 is edge id.
// Pass 1 issues 32 independent coalesced k-row loads (deep MLP), pass 2
// re-gathers v (L2/L3-warm). Softmax math identical to prior rounds (fp32).
// ---------------------------------------------------------------------------
__global__ __launch_bounds__(256) void edge_kernel(
    const u16* __restrict__ qkv,        // [N, 1664] bf16
    const int* __restrict__ col_index, const int* __restrict__ to_col,
    const float* __restrict__ att_bias, const float* __restrict__ dist,
    const float* __restrict__ pos, const float* __restrict__ col_pos,
    u16* __restrict__ feat)             // [N, 576] bf16 (544 used)
{
    const int wave = threadIdx.x >> 6;
    const int lane = threadIdx.x & 63;
    const int n0 = (blockIdx.x * 4 + wave) * 2;
    const int n1 = n0 + 1;
    const int h = lane >> 3;
    const int sub = lane & 7;
    const int hoff = lane * 8;            // == h*DKH + sub*8

    // q fragments (8 dims each node), fp32
    float qf0[8], qf1[8];
    {
        const us8 qu0 = *(const us8*)(qkv + (size_t)n0 * QKV_W + hoff);
        const us8 qu1 = *(const us8*)(qkv + (size_t)n1 * QKV_W + hoff);
        #pragma unroll
        for (int i = 0; i < 8; ++i) { qf0[i] = bf2f(qu0[i]); qf1[i] = bf2f(qu1[i]); }
    }
    // qv (3 per head) via wave shuffle from the 24 bf16 at col 1536
    float qv00, qv01, qv02, qv10, qv11, qv12;
    {
        const int qc = (lane < 24 ? lane : 0);
        const float a = bf2f(qkv[(size_t)n0 * QKV_W + 1536 + qc]);
        const float b = bf2f(qkv[(size_t)n1 * QKV_W + 1536 + qc]);
        qv00 = __shfl(a, h * 3 + 0); qv01 = __shfl(a, h * 3 + 1); qv02 = __shfl(a, h * 3 + 2);
        qv10 = __shfl(b, h * 3 + 0); qv11 = __shfl(b, h * 3 + 1); qv12 = __shfl(b, h * 3 + 2);
    }
    const float px0 = pos[3 * n0 + 0], py0 = pos[3 * n0 + 1], pz0 = pos[3 * n0 + 2];
    const float px1 = pos[3 * n1 + 0], py1 = pos[3 * n1 + 1], pz1 = pos[3 * n1 + 2];

    // per-edge metadata: lanes 0..15 -> n0 edges, 16..31 -> n1 edges
    // (lanes 32..63 hold duplicates)
    const int gm  = (lane >> 4) & 1;
    const int j16 = lane & 15;
    const int nm  = n0 + gm;
    const int em  = nm * DEG + j16;
    const int c_l  = col_index[em];
    const int cc_l = to_col[c_l];
    const float d_l = dist[em];
    const float invd_l = (d_l == 0.f) ? 0.f : (1.f / d_l);
    const float rx_l = col_pos[3 * c_l + 0] - (gm ? px1 : px0);
    const float ry_l = col_pos[3 * c_l + 1] - (gm ? py1 : py0);
    const float rz_l = col_pos[3 * c_l + 2] - (gm ? pz1 : pz0);

    // bias: lane (h,sub) preloads edges sub*2, sub*2+1 of head h, both nodes
    const float b00 = att_bias[(size_t)h * E_EDGES + n0 * DEG + sub * 2 + 0];
    const float b01 = att_bias[(size_t)h * E_EDGES + n0 * DEG + sub * 2 + 1];
    const float b10 = att_bias[(size_t)h * E_EDGES + n1 * DEG + sub * 2 + 0];
    const float b11 = att_bias[(size_t)h * E_EDGES + n1 * DEG + sub * 2 + 1];

    // ---- pass 1: 32 independent k-row loads + logits -----------------------
    float logit0[DEG], logit1[DEG];
    #pragma unroll
    for (int j = 0; j < DEG; ++j) {
        const int cc0 = __shfl(cc_l, j);
        const int cc1 = __shfl(cc_l, 16 + j);
        const us8 ku0 = *(const us8*)(qkv + (size_t)cc0 * QKV_W + 512 + hoff);
        const us8 ku1 = *(const us8*)(qkv + (size_t)cc1 * QKV_W + 512 + hoff);
        float dot0 = 0.f, dot1 = 0.f;
        #pragma unroll
        for (int i = 0; i < 8; ++i) {
            dot0 += qf0[i] * bf2f(ku0[i]);
            dot1 += qf1[i] * bf2f(ku1[i]);
        }
        dot0 += __shfl_xor(dot0, 1, 8); dot1 += __shfl_xor(dot1, 1, 8);
        dot0 += __shfl_xor(dot0, 2, 8); dot1 += __shfl_xor(dot1, 2, 8);
        dot0 += __shfl_xor(dot0, 4, 8); dot1 += __shfl_xor(dot1, 4, 8);
        const float ang0 = qv00 * __shfl(rx_l, j) + qv01 * __shfl(ry_l, j)
                         + qv02 * __shfl(rz_l, j);
        const float ang1 = qv10 * __shfl(rx_l, 16 + j) + qv11 * __shfl(ry_l, 16 + j)
                         + qv12 * __shfl(rz_l, 16 + j);
        const float bj0 = __shfl((j & 1) ? b01 : b00, j >> 1, 8);
        const float bj1 = __shfl((j & 1) ? b11 : b10, j >> 1, 8);
        logit0[j] = dot0 + bj0 + ang0 * __shfl(invd_l, j);
        logit1[j] = dot1 + bj1 + ang1 * __shfl(invd_l, 16 + j);
    }

    // ---- softmax over 16 edges, each node ----------------------------------
    float m0 = logit0[0], m1 = logit1[0];
    #pragma unroll
    for (int j = 1; j < DEG; ++j) { m0 = fmaxf(m0, logit0[j]); m1 = fmaxf(m1, logit1[j]); }
    float s0 = 0.f, s1 = 0.f;
    #pragma unroll
    for (int j = 0; j < DEG; ++j) {
        logit0[j] = __expf(logit0[j] - m0); s0 += logit0[j];
        logit1[j] = __expf(logit1[j] - m1); s1 += logit1[j];
    }
    const float is0 = 1.f / s0, is1 = 1.f / s1;

    // ---- pass 2: v re-gather + weighted accumulation -----------------------
    float y0[8] = {0,0,0,0,0,0,0,0}, y1[8] = {0,0,0,0,0,0,0,0};
    float dx0 = 0.f, dy0 = 0.f, dz0 = 0.f, a0 = 0.f;
    float dx1 = 0.f, dy1 = 0.f, dz1 = 0.f, a1 = 0.f;
    #pragma unroll
    for (int j = 0; j < DEG; ++j) {
        const int cc0 = __shfl(cc_l, j);
        const int cc1 = __shfl(cc_l, 16 + j);
        const us8 vu0 = *(const us8*)(qkv + (size_t)cc0 * QKV_W + 1024 + hoff);
        const us8 vu1 = *(const us8*)(qkv + (size_t)cc1 * QKV_W + 1024 + hoff);
        const float w0 = logit0[j] * is0;
        const float w1 = logit1[j] * is1;
        #pragma unroll
        for (int i = 0; i < 8; ++i) {
            y0[i] += w0 * bf2f(vu0[i]);
            y1[i] += w1 * bf2f(vu1[i]);
        }
        const float na0 = w0 * __shfl(invd_l, j);
        const float na1 = w1 * __shfl(invd_l, 16 + j);
        dx0 += na0 * __shfl(rx_l, j);       dx1 += na1 * __shfl(rx_l, 16 + j);
        dy0 += na0 * __shfl(ry_l, j);       dy1 += na1 * __shfl(ry_l, 16 + j);
        dz0 += na0 * __shfl(rz_l, j);       dz1 += na1 * __shfl(rz_l, 16 + j);
        a0 += na0;                          a1 += na1;
    }

    // ---- write feat (stride 576; pad cols never read against nonzero W) ----
    {
        u16* f = feat + (size_t)n0 * FEAT_W + h * (DKH + 4);
        ushort4 o0, o1;
        o0.x = f2bf(y0[0]); o0.y = f2bf(y0[1]); o0.z = f2bf(y0[2]); o0.w = f2bf(y0[3]);
        o1.x = f2bf(y0[4]); o1.y = f2bf(y0[5]); o1.z = f2bf(y0[6]); o1.w = f2bf(y0[7]);
        *(ushort4*)(f + sub * 8 + 0) = o0;
        *(ushort4*)(f + sub * 8 + 4) = o1;
        if (sub == 0) {
            const float nrm = sqrtf(dx0 * dx0 + dy0 * dy0 + dz0 * dz0);
            const float rn = 1.f / fmaxf(nrm, 1e-12f);
            ushort4 ex;
            ex.x = f2bf(dx0 * rn); ex.y = f2bf(dy0 * rn);
            ex.z = f2bf(dz0 * rn); ex.w = f2bf(a0);
            *(ushort4*)(f + DKH) = ex;
        }
    }
    {
        u16* f = feat + (size_t)n1 * FEAT_W + h * (DKH + 4);
        ushort4 o0, o1;
        o0.x = f2bf(y1[0]); o0.y = f2bf(y1[1]); o0.z = f2bf(y1[2]); o0.w = f2bf(y1[3]);
        o1.x = f2bf(y1[4]); o1.y = f2bf(y1[5]); o1.z = f2bf(y1[6]); o1.w = f2bf(y1[7]);
        *(ushort4*)(f + sub * 8 + 0) = o0;
        *(ushort4*)(f + sub * 8 + 4) = o1;
        if (sub == 0) {
            const float nrm = sqrtf(dx1 * dx1 + dy1 * dy1 + dz1 * dz1);
            const float rn = 1.f / fmaxf(nrm, 1e-12f);
            ushort4 ex;
            ex.x = f2bf(dx1 * rn); ex.y = f2bf(dy1 * rn);
            ex.z = f2bf(dz1 * rn); ex.w = f2bf(a1);
            *(ushort4*)(f + DKH) = ex;
        }
    }
}

// ---------------------------------------------------------------------------
extern "C" void kernel_launch(void* const* d_in, const int* in_sizes, int n_in,
                              void* d_out, int out_size, void* d_ws, size_t ws_size,
                              hipStream_t stream)
{
    const float* x         = (const float*)d_in[0];
    const int*   col_index = (const int*)d_in[2];
    const int*   to_col    = (const int*)d_in[3];
    const float* att_bias  = (const float*)d_in[4];
    const float* dist      = (const float*)d_in[5];
    const float* pos       = (const float*)d_in[6];
    const float* col_pos   = (const float*)d_in[7];
    const float* Wq        = (const float*)d_in[8];
    const float* Wqv       = (const float*)d_in[9];
    const float* Wk        = (const float*)d_in[10];
    const float* Wv        = (const float*)d_in[11];
    const float* Wout      = (const float*)d_in[12];
    const float* bout      = (const float*)d_in[13];
    float* out = (float*)d_out;

    // Workspace layout (bytes), total ~48 MB
    char* ws = (char*)d_ws;
    u16* qkv   = (u16*)(ws + 0);           // [8192,1664] bf16  27,262,976
    u16* xh    = (u16*)(ws + 27262976);    // [8192,512]  bf16   8,388,608
    u16* Bfuse = (u16*)(ws + 35651584);    // [1664,512]  bf16   1,703,936
    u16* Woth  = (u16*)(ws + 37355520);    // [512,576]   bf16     589,824
    u16* Wotl  = (u16*)(ws + 37945344);    // [512,576]   bf16     589,824
    u16* feat  = (u16*)(ws + 38535168);    // [8192,576]  bf16   9,437,184

    dim3 blk(256);

    // Fused prep (x cvt + build B + Wout split w/ 576 pad)
    hipLaunchKernelGGL(prep_kernel, dim3(5216), blk, 0, stream,
                       x, Wq, Wk, Wv, Wqv, Wout, xh, Bfuse, Woth, Wotl);

    // Fused q|k|v|qv projection: [8192,1664] bf16, 1-pass, BK=64
    hipLaunchKernelGGL((gemm_mfma<false, true>), dim3(QKV_W / 128, N_NODES / 128),
                       blk, 0, stream,
                       xh, Bfuse, (const u16*)nullptr, (const float*)nullptr,
                       (void*)qkv, N_NODES, QKV_W, D_FEAT);

    // Edge stage: 2 nodes per wave, two-pass re-gather
    hipLaunchKernelGGL(edge_kernel, dim3(N_NODES / 8), blk, 0, stream,
                       qkv, col_index, to_col, att_bias, dist, pos, col_pos, feat);

    // Output GEMM: out = feat(bf16,K=576) @ (Woth+Wotl)^T + bout, 2-pass, BK=64
    hipLaunchKernelGGL((gemm_mfma<true, false>), dim3(OUT_W / 128, N_NODES / 128),
                       blk, 0, stream,
                       feat, Woth, Wotl, bout, (void*)out,
                       N_NODES, OUT_W, FEAT_W);
}

// Round 7
// 173.912 us; speedup vs baseline: 1.3013x; 1.3013x over previous
//
#include <hip/hip_runtime.h>
#include <math.h>

#define N_NODES 8192
#define D_FEAT  512
#define H_HEADS 8
#define DKH     64
#define DEG     16
#define E_EDGES (N_NODES * DEG)
#define FEAT_W  576      // 544 used (8*(64+4)) + 32 pad for K%64==0
#define FEAT_USED 544
#define OUT_W   512
#define QKV_W   1664     // 512 q | 512 k | 512 v | 24 qv | 104 pad  (13*128)

typedef unsigned short u16;
typedef __attribute__((ext_vector_type(8))) short short8;   // 8 bf16 for MFMA
typedef __attribute__((ext_vector_type(8))) unsigned short us8;
typedef __attribute__((ext_vector_type(4))) float f32x4;

// ---- bf16 helpers (RNE) ----------------------------------------------------
__device__ __forceinline__ u16 f2bf(float f) {
    union { float f; unsigned u; } c; c.f = f;
    unsigned u = c.u;
    unsigned r = u + 0x7FFFu + ((u >> 16) & 1u);
    return (u16)(r >> 16);
}
__device__ __forceinline__ float bf2f(u16 h) {
    union { unsigned u; float f; } c; c.u = ((unsigned)h) << 16;
    return c.f;
}

// ---- async global->LDS 16B (HW: lds dest = wave-uniform base + lane*16) ----
__device__ __forceinline__ void async16(const void* g, void* l) {
    __builtin_amdgcn_global_load_lds(
        (const __attribute__((address_space(1))) void*)g,
        (__attribute__((address_space(3))) void*)l, 16, 0, 0);
}

// ---------------------------------------------------------------------------
// bf16 MFMA GEMM, BK=64: C[M,N] = A[M,K]*B[N,K]^T (+bias). Optional split-B
// second pass (B = Bh + Bl). M%128==0, N%128==0, K%64==0.
// 1-D grid, XCD-swizzled: flat%8 keys the XCD (dispatch is round-robin), and
// all N-tiles of one M-tile land on the same XCD -> A panel is fetched from
// HBM once per tile and re-served from that XCD's L2.  M/128 must be %8.
// LDS tiles [128][64] u16, 16B-chunk XOR-swizzle by (row&7) applied to the
// *global source address* (global_load_lds dest is fixed base+lane*16).
// ---------------------------------------------------------------------------
template<bool HAS_BL, bool BF16_OUT>
__global__ __launch_bounds__(256) void gemm_mfma(
    const u16* __restrict__ Ah,
    const u16* __restrict__ Bh, const u16* __restrict__ Bl,
    const float* __restrict__ bias, void* __restrict__ Cout,
    int M, int N, int K)
{
    constexpr int NMAT = HAS_BL ? 3 : 2;
    __shared__ u16 smem[128 * 64 * NMAT];
    u16* sAh = smem;
    u16* sBh = smem + 128 * 64;
    u16* sBl = smem + 128 * 64 * 2;   // used only if HAS_BL

    const int tid  = threadIdx.x;
    // XCD-aware block swizzle
    const int ntiles = N >> 7;
    const int flat = blockIdx.x;
    const int xcd  = flat & 7;
    const int rr   = flat >> 3;
    const int bm   = (xcd + 8 * (rr / ntiles)) * 128;
    const int bn   = (rr % ntiles) * 128;

    const int wave = tid >> 6;
    const int lane = tid & 63;
    const int wr   = (wave >> 1) * 64;
    const int wc   = (wave & 1) * 64;
    const int lrow = lane & 15;
    const int quad = lane >> 4;

    f32x4 acc[4][4];
    #pragma unroll
    for (int i = 0; i < 4; ++i)
        #pragma unroll
        for (int j = 0; j < 4; ++j) {
            f32x4 z = {0.f, 0.f, 0.f, 0.f};
            acc[i][j] = z;
        }

    for (int k0 = 0; k0 < K; k0 += 64) {
        // Stage 128x64 u16 per matrix = 1024 16B chunks; 4 per thread each.
        #pragma unroll
        for (int i = 0; i < 4; ++i) {
            const int lin = i * 256 + tid;            // LDS chunk slot 0..1023
            const int row = lin >> 3;                 // 0..127
            const int cs  = lin & 7;                  // swizzled chunk in row
            const int cu  = cs ^ (row & 7);           // unswizzled k-chunk
            const int seg = cu << 3;                  // k element offset
            const int loff = lin << 3;                // lane-linear 16B dest
            const size_t ga = (size_t)(bm + row) * K + k0 + seg;
            const size_t gb = (size_t)(bn + row) * K + k0 + seg;
            async16(Ah + ga, sAh + loff);
            async16(Bh + gb, sBh + loff);
            if (HAS_BL) async16(Bl + gb, sBl + loff);
        }
        __syncthreads();

        #pragma unroll
        for (int ko = 0; ko < 64; ko += 32) {
            const int cbase = ko >> 3;                // 0 or 4
            short8 a_h[4], b_h[4], b_l[4];
            #pragma unroll
            for (int t = 0; t < 4; ++t) {
                const int ra = wr + t * 16 + lrow;
                const int rb = wc + t * 16 + lrow;
                const int ca = ((cbase + quad) ^ (ra & 7)) << 3;
                const int cb = ((cbase + quad) ^ (rb & 7)) << 3;
                a_h[t] = *(const short8*)&sAh[ra * 64 + ca];
                b_h[t] = *(const short8*)&sBh[rb * 64 + cb];
                if (HAS_BL) b_l[t] = *(const short8*)&sBl[rb * 64 + cb];
            }
            #pragma unroll
            for (int mt = 0; mt < 4; ++mt)
                #pragma unroll
                for (int nt = 0; nt < 4; ++nt) {
                    acc[mt][nt] = __builtin_amdgcn_mfma_f32_16x16x32_bf16(
                        a_h[mt], b_h[nt], acc[mt][nt], 0, 0, 0);
                    if (HAS_BL)
                        acc[mt][nt] = __builtin_amdgcn_mfma_f32_16x16x32_bf16(
                            a_h[mt], b_l[nt], acc[mt][nt], 0, 0, 0);
                }
        }
        __syncthreads();
    }

    // C/D layout: col = lane&15, row = quad*4 + r
    #pragma unroll
    for (int nt = 0; nt < 4; ++nt) {
        const int col = bn + wc + nt * 16 + lrow;
        const float bb = bias ? bias[col] : 0.f;
        #pragma unroll
        for (int mt = 0; mt < 4; ++mt) {
            #pragma unroll
            for (int r = 0; r < 4; ++r) {
                const int row = bm + wr + mt * 16 + quad * 4 + r;
                const float v = acc[mt][nt][r] + bb;
                if (BF16_OUT)
                    ((u16*)Cout)[(size_t)row * N + col] = f2bf(v);
                else
                    ((float*)Cout)[(size_t)row * N + col] = v;
            }
        }
    }
}

// ---------------------------------------------------------------------------
// Fused prep: block-range partition over three jobs.
//  blocks [0, 4096)      : x fp32 -> bf16                 (1048576 ushort4)
//  blocks [4096, 4928)   : build fused B [1664,512]       (212992 ushort4)
//  blocks [4928, 5216)   : Wout -> bf16 [512,576] pad0    (73728 ushort4)
// ---------------------------------------------------------------------------
__global__ __launch_bounds__(256) void prep_kernel(
    const float* __restrict__ x,
    const float* __restrict__ Wq, const float* __restrict__ Wk,
    const float* __restrict__ Wv, const float* __restrict__ Wqv,
    const float* __restrict__ Wout,
    u16* __restrict__ xh, u16* __restrict__ B, u16* __restrict__ Woth)
{
    const int b = blockIdx.x;
    const int tid = threadIdx.x;
    if (b < 4096) {
        const int i = b * 256 + tid;                 // < 1048576
        const float4 v = ((const float4*)x)[i];
        ushort4 h;
        h.x = f2bf(v.x); h.y = f2bf(v.y); h.z = f2bf(v.z); h.w = f2bf(v.w);
        ((ushort4*)xh)[i] = h;
    } else if (b < 4928) {
        const int idx = (b - 4096) * 256 + tid;      // < 212992
        const int row = idx >> 7;
        const int c4  = idx & 127;
        float4 v = make_float4(0.f, 0.f, 0.f, 0.f);
        float scale = 1.f;
        if (row < 512) {
            v = *(const float4*)(Wq + (size_t)row * 512 + c4 * 4);
            scale = 0.125f;                          // 1/sqrt(64) folded into Wq
        } else if (row < 1024) {
            v = *(const float4*)(Wk + (size_t)(row - 512) * 512 + c4 * 4);
        } else if (row < 1536) {
            v = *(const float4*)(Wv + (size_t)(row - 1024) * 512 + c4 * 4);
        } else if (row < 1560) {
            v = *(const float4*)(Wqv + (size_t)(row - 1536) * 512 + c4 * 4);
        }
        ushort4 h;
        h.x = f2bf(v.x * scale); h.y = f2bf(v.y * scale);
        h.z = f2bf(v.z * scale); h.w = f2bf(v.w * scale);
        ((ushort4*)B)[idx] = h;
    } else {
        const int i = (b - 4928) * 256 + tid;        // < 73728 = 512*576/4
        if (i >= OUT_W * FEAT_W / 4) return;
        const int row = i / (FEAT_W / 4);            // /144
        const int c4  = i % (FEAT_W / 4);
        float4 v = make_float4(0.f, 0.f, 0.f, 0.f);
        if (c4 < FEAT_USED / 4)                      // pad cols 544..575 = 0
            v = *(const float4*)(Wout + (size_t)row * FEAT_USED + c4 * 4);
        ushort4 h;
        h.x = f2bf(v.x); h.y = f2bf(v.y);
        h.z = f2bf(v.z); h.w = f2bf(v.w);
        ((ushort4*)Woth)[i] = h;
    }
}

// ---------------------------------------------------------------------------
// Edge stage (round-5 proven config): ONE WAVE PER NODE, two-pass with LDS
// v-staging. lane = h*8+sub owns dims [lane*8, lane*8+8) of the 512-dim row.
// Pass 1: per edge, k row -> VGPR (dot) AND v row -> LDS via global_load_lds
// (dest = wave-uniform base + lane*16, matching layout; zero VGPR cost).
// Pass 2: softmax in regs, v read from LDS (no re-gather).
// ---------------------------------------------------------------------------
#define EK_WAVES 2   // 16 KB LDS per wave; 32 KB/block -> 5 blocks/CU
__global__ __launch_bounds__(EK_WAVES * 64) void edge_kernel(
    const u16* __restrict__ qkv,        // [N, 1664] bf16
    const int* __restrict__ col_index, const int* __restrict__ to_col,
    const float* __restrict__ att_bias, const float* __restrict__ dist,
    const float* __restrict__ pos, const float* __restrict__ col_pos,
    u16* __restrict__ feat)             // [N, 576] bf16 (544 used)
{
    __shared__ u16 vbuf[EK_WAVES * DEG * 512];

    const int wave = threadIdx.x >> 6;
    const int lane = threadIdx.x & 63;
    const int n = blockIdx.x * EK_WAVES + wave;
    const int h = lane >> 3;
    const int sub = lane & 7;

    const size_t qbase = (size_t)n * QKV_W;
    const int hoff = lane * 8;            // == h*DKH + sub*8

    // q fragment (8 dims), fp32
    float qf[8];
    {
        const us8 qu = *(const us8*)(qkv + qbase + hoff);
        #pragma unroll
        for (int i = 0; i < 8; ++i) qf[i] = bf2f(qu[i]);
    }
    // qv (3 per head) via wave shuffle from the 24 bf16 at col 1536
    float qv0, qv1, qv2;
    {
        const float qvl = bf2f(qkv[qbase + 1536 + (lane < 24 ? lane : 0)]);
        qv0 = __shfl(qvl, h * 3 + 0);
        qv1 = __shfl(qvl, h * 3 + 1);
        qv2 = __shfl(qvl, h * 3 + 2);
    }
    const float px = pos[3 * n + 0], py = pos[3 * n + 1], pz = pos[3 * n + 2];

    // per-edge metadata in lanes 0..15 (lanes 16+ hold duplicates)
    const int j16 = lane & 15;
    const int e0  = n * DEG + j16;
    const int c_l  = col_index[e0];
    const int cc_l = to_col[c_l];
    const float d_l = dist[e0];
    const float invd_l = (d_l == 0.f) ? 0.f : (1.f / d_l);
    const float rx_l = col_pos[3 * c_l + 0] - px;
    const float ry_l = col_pos[3 * c_l + 1] - py;
    const float rz_l = col_pos[3 * c_l + 2] - pz;

    // bias: lane (h,sub) preloads edges sub*2, sub*2+1 of head h
    const float b0 = att_bias[(size_t)h * E_EDGES + n * DEG + sub * 2 + 0];
    const float b1 = att_bias[(size_t)h * E_EDGES + n * DEG + sub * 2 + 1];

    // ---- pass 1: k dot (VGPR) + v row -> LDS (async), all independent ------
    float logit[DEG];
    u16* vb = &vbuf[wave * DEG * 512];
    #pragma unroll
    for (int j = 0; j < DEG; ++j) {
        const int cc = __shfl(cc_l, j);
        const u16* rowp = qkv + (size_t)cc * QKV_W + hoff;
        async16(rowp + 1024, vb + j * 512);          // v row -> LDS
        const us8 ku = *(const us8*)(rowp + 512);    // k row -> regs
        float dot = 0.f;
        #pragma unroll
        for (int i = 0; i < 8; ++i) dot += qf[i] * bf2f(ku[i]);
        dot += __shfl_xor(dot, 1, 8);
        dot += __shfl_xor(dot, 2, 8);
        dot += __shfl_xor(dot, 4, 8);
        const float invd = __shfl(invd_l, j);
        const float ang = qv0 * __shfl(rx_l, j) + qv1 * __shfl(ry_l, j)
                        + qv2 * __shfl(rz_l, j);
        const float bj = __shfl((j & 1) ? b1 : b0, j >> 1, 8);
        logit[j] = dot + bj + ang * invd;
    }

    // ---- softmax over 16 edges (replicated across the 8 dim-lanes) ---------
    float m = logit[0];
    #pragma unroll
    for (int j = 1; j < DEG; ++j) m = fmaxf(m, logit[j]);
    float s = 0.f;
    #pragma unroll
    for (int j = 0; j < DEG; ++j) { logit[j] = __expf(logit[j] - m); s += logit[j]; }
    const float inv_s = 1.f / s;

    __syncthreads();   // drain global_load_lds (vmcnt) + make LDS visible

    // ---- pass 2: weighted accumulation from LDS ----------------------------
    float y[8] = {0.f, 0.f, 0.f, 0.f, 0.f, 0.f, 0.f, 0.f};
    float dx = 0.f, dy = 0.f, dz = 0.f, aid = 0.f;
    #pragma unroll
    for (int j = 0; j < DEG; ++j) {
        const float a = logit[j] * inv_s;
        const us8 vu = *(const us8*)&vb[j * 512 + hoff];
        #pragma unroll
        for (int i = 0; i < 8; ++i) y[i] += a * bf2f(vu[i]);
        const float na = a * __shfl(invd_l, j);
        dx += na * __shfl(rx_l, j);      // dst_vec - src_vec == sum na*rel
        dy += na * __shfl(ry_l, j);
        dz += na * __shfl(rz_l, j);
        aid += na;
    }

    // ---- write feat (stride 576) -------------------------------------------
    u16* f = feat + (size_t)n * FEAT_W + h * (DKH + 4);
    ushort4 o0, o1;
    o0.x = f2bf(y[0]); o0.y = f2bf(y[1]); o0.z = f2bf(y[2]); o0.w = f2bf(y[3]);
    o1.x = f2bf(y[4]); o1.y = f2bf(y[5]); o1.z = f2bf(y[6]); o1.w = f2bf(y[7]);
    *(ushort4*)(f + sub * 8 + 0) = o0;
    *(ushort4*)(f + sub * 8 + 4) = o1;
    if (sub == 0) {
        const float nrm = sqrtf(dx * dx + dy * dy + dz * dz);
        const float rn = 1.f / fmaxf(nrm, 1e-12f);
        ushort4 ex;
        ex.x = f2bf(dx * rn); ex.y = f2bf(dy * rn);
        ex.z = f2bf(dz * rn); ex.w = f2bf(aid);
        *(ushort4*)(f + DKH) = ex;
    }
}

// ---------------------------------------------------------------------------
extern "C" void kernel_launch(void* const* d_in, const int* in_sizes, int n_in,
                              void* d_out, int out_size, void* d_ws, size_t ws_size,
                              hipStream_t stream)
{
    const float* x         = (const float*)d_in[0];
    const int*   col_index = (const int*)d_in[2];
    const int*   to_col    = (const int*)d_in[3];
    const float* att_bias  = (const float*)d_in[4];
    const float* dist      = (const float*)d_in[5];
    const float* pos       = (const float*)d_in[6];
    const float* col_pos   = (const float*)d_in[7];
    const float* Wq        = (const float*)d_in[8];
    const float* Wqv       = (const float*)d_in[9];
    const float* Wk        = (const float*)d_in[10];
    const float* Wv        = (const float*)d_in[11];
    const float* Wout      = (const float*)d_in[12];
    const float* bout      = (const float*)d_in[13];
    float* out = (float*)d_out;

    // Workspace layout (bytes), total ~47.5 MB
    char* ws = (char*)d_ws;
    u16* qkv   = (u16*)(ws + 0);           // [8192,1664] bf16  27,262,976
    u16* xh    = (u16*)(ws + 27262976);    // [8192,512]  bf16   8,388,608
    u16* Bfuse = (u16*)(ws + 35651584);    // [1664,512]  bf16   1,703,936
    u16* Woth  = (u16*)(ws + 37355520);    // [512,576]   bf16     589,824
    u16* feat  = (u16*)(ws + 37945344);    // [8192,576]  bf16   9,437,184

    dim3 blk(256);

    // Fused prep (x cvt + build B + Wout bf16 w/ 576 pad)
    hipLaunchKernelGGL(prep_kernel, dim3(5216), blk, 0, stream,
                       x, Wq, Wk, Wv, Wqv, Wout, xh, Bfuse, Woth);

    // Fused q|k|v|qv projection: [8192,1664] bf16, 1-pass, BK=64, XCD-swizzled
    hipLaunchKernelGGL((gemm_mfma<false, true>), dim3((N_NODES / 128) * (QKV_W / 128)),
                       blk, 0, stream,
                       xh, Bfuse, (const u16*)nullptr, (const float*)nullptr,
                       (void*)qkv, N_NODES, QKV_W, D_FEAT);

    // Edge stage: wave per node, two-pass + LDS v-staging (round-5 config)
    hipLaunchKernelGGL(edge_kernel, dim3(N_NODES / EK_WAVES), dim3(EK_WAVES * 64),
                       0, stream,
                       qkv, col_index, to_col, att_bias, dist, pos, col_pos, feat);

    // Output GEMM: out = feat(bf16,K=576) @ Woth^T + bout, 1-pass, XCD-swizzled
    hipLaunchKernelGGL((gemm_mfma<false, false>), dim3((N_NODES / 128) * (OUT_W / 128)),
                       blk, 0, stream,
                       feat, Woth, (const u16*)nullptr, bout, (void*)out,
                       N_NODES, OUT_W, FEAT_W);
}